// Round 11
// baseline (508.543 us; speedup 1.0000x reference)
//
#include <hip/hip_runtime.h>
#include <cstdint>

#define ND 16384
#define BATCH 4096
#define CDIM 768
#define E_DD 131072
#define FD 256

typedef unsigned short u16;
typedef u16 u16x4 __attribute__((ext_vector_type(4)));
typedef u16 u16x8 __attribute__((ext_vector_type(8)));
typedef short s16x8 __attribute__((ext_vector_type(8)));
typedef float f32x4 __attribute__((ext_vector_type(4)));

__device__ __forceinline__ u16 f2bf(float x) {
  union { float f; uint32_t u; } v; v.f = x;
  uint32_t r = v.u + 0x7fffu + ((v.u >> 16) & 1u);
  return (u16)(r >> 16);
}
__device__ __forceinline__ float bf2f(u16 h) {
  union { float f; uint32_t u; } v; v.u = ((uint32_t)h) << 16;
  return v.f;
}
// (hi << 16) | lo ; hi = bf16(x), lo = bf16(x - hi)
__device__ __forceinline__ uint32_t split2p(float x) {
  u16 h = f2bf(x);
  u16 l = f2bf(x - bf2f(h));
  return ((uint32_t)h << 16) | l;
}

// ---------------------------------------------------------------------------
// MFMA GEMM, 128x128 tile, BK=32, 4 waves (2x2), MT=NT=4, 16x16x32 bf16.
// R5-proven core: coalesced staging (4 threads/row cover 64B), KP=40 pitch.
// Precision ladder per operand (validated R9/R10):
//   ALO / BLO: operand has hi+lo error-compensation terms.
// ASPLIT: A given as fp32, split on load (implies ALO=1).
// OUT_BF16: epilogue writes round-to-nearest bf16.
// KS>1: split-K partial mode — blockIdx.z K-chunk, partial at Cf + z*M*N.
// ---------------------------------------------------------------------------
#define KP 40

template <int KS, int OUT_BF16, int RELU, int BIAS, int ASPLIT, int ALO, int BLO>
__global__ __launch_bounds__(256) void mfma_gemm(
    const float* __restrict__ Af,
    const u16* __restrict__ Ahi, const u16* __restrict__ Alo,
    const u16* __restrict__ Bhi, const u16* __restrict__ Blo,
    const float* __restrict__ bias,
    float* __restrict__ Cf, u16* __restrict__ Chi,
    int M, int N, int K) {
  constexpr int MT = 4, NT = 4;
  constexpr int BM = 128, BN = 128;
  constexpr int ASEG = BM / 64;
  constexpr int BSEG = BN / 64;
  constexpr int AARR = ALO ? 2 : 1;
  constexpr int BARR = BLO ? 2 : 1;
  __shared__ __align__(16) u16 As[AARR][BM][KP];
  __shared__ __align__(16) u16 Bs[BARR][BN][KP];

  const int t = threadIdx.x;
  const int bm0 = blockIdx.x * BM, bn0 = blockIdx.y * BN;
  const int wid = t >> 6, lane = t & 63;
  const int quad = lane >> 4, l16 = lane & 15;
  const int wm0 = (wid >> 1) * (MT * 16);
  const int wn0 = (wid & 1) * (NT * 16);

  const int chunk = K / KS;
  const int kbeg = (KS > 1) ? (int)blockIdx.z * chunk : 0;
  const int kend = kbeg + chunk;

  f32x4 acc[MT][NT];
#pragma unroll
  for (int i = 0; i < MT; ++i)
#pragma unroll
    for (int j = 0; j < NT; ++j) acc[i][j] = (f32x4){0.f, 0.f, 0.f, 0.f};

  u16x8 pAh[ASEG], pAl[ASEG], pBh[BSEG], pBl[BSEG];

  auto loadA = [&](int c, int kk) {
    int s = t + 256 * c, row = s >> 2, kq = (s & 3) * 8;
    size_t off = (size_t)(bm0 + row) * K + kk + kq;
    if (ASPLIT) {
      f32x4 v0 = *(const f32x4*)(Af + off);
      f32x4 v1 = *(const f32x4*)(Af + off + 4);
      u16x8 h, l;
#pragma unroll
      for (int e = 0; e < 4; ++e) {
        uint32_t p = split2p(v0[e]);
        h[e] = (u16)(p >> 16); l[e] = (u16)(p & 0xffffu);
        uint32_t q = split2p(v1[e]);
        h[e + 4] = (u16)(q >> 16); l[e + 4] = (u16)(q & 0xffffu);
      }
      pAh[c] = h; pAl[c] = l;
    } else {
      pAh[c] = *(const u16x8*)(Ahi + off);
      if (ALO) pAl[c] = *(const u16x8*)(Alo + off);
    }
  };
  auto loadB = [&](int c, int kk) {
    int s = t + 256 * c, row = s >> 2, kq = (s & 3) * 8;
    size_t off = (size_t)(bn0 + row) * K + kk + kq;
    pBh[c] = *(const u16x8*)(Bhi + off);
    if (BLO) pBl[c] = *(const u16x8*)(Blo + off);
  };

#pragma unroll
  for (int c = 0; c < ASEG; ++c) loadA(c, kbeg);
#pragma unroll
  for (int c = 0; c < BSEG; ++c) loadB(c, kbeg);

  for (int k0 = kbeg;;) {
    __syncthreads();
#pragma unroll
    for (int c = 0; c < ASEG; ++c) {
      int s = t + 256 * c, row = s >> 2, kq = (s & 3) * 8;
      *(u16x8*)&As[0][row][kq] = pAh[c];
      if (ALO) *(u16x8*)&As[AARR - 1][row][kq] = pAl[c];
    }
#pragma unroll
    for (int c = 0; c < BSEG; ++c) {
      int s = t + 256 * c, row = s >> 2, kq = (s & 3) * 8;
      *(u16x8*)&Bs[0][row][kq] = pBh[c];
      if (BLO) *(u16x8*)&Bs[BARR - 1][row][kq] = pBl[c];
    }
    __syncthreads();

    int kn = k0 + 32;
    if (kn < kend) {
#pragma unroll
      for (int c = 0; c < ASEG; ++c) loadA(c, kn);
#pragma unroll
      for (int c = 0; c < BSEG; ++c) loadB(c, kn);
    }

    s16x8 ah[MT], al[MT], bh[NT], bl[NT];
#pragma unroll
    for (int mi = 0; mi < MT; ++mi) {
      ah[mi] = *(const s16x8*)&As[0][wm0 + mi * 16 + l16][quad * 8];
      if (ALO) al[mi] = *(const s16x8*)&As[AARR - 1][wm0 + mi * 16 + l16][quad * 8];
    }
#pragma unroll
    for (int ni = 0; ni < NT; ++ni) {
      bh[ni] = *(const s16x8*)&Bs[0][wn0 + ni * 16 + l16][quad * 8];
      if (BLO) bl[ni] = *(const s16x8*)&Bs[BARR - 1][wn0 + ni * 16 + l16][quad * 8];
    }
#pragma unroll
    for (int mi = 0; mi < MT; ++mi)
#pragma unroll
      for (int ni = 0; ni < NT; ++ni) {
        acc[mi][ni] = __builtin_amdgcn_mfma_f32_16x16x32_bf16(
            ah[mi], bh[ni], acc[mi][ni], 0, 0, 0);
        if (BLO)
          acc[mi][ni] = __builtin_amdgcn_mfma_f32_16x16x32_bf16(
              ah[mi], bl[ni], acc[mi][ni], 0, 0, 0);
        if (ALO)
          acc[mi][ni] = __builtin_amdgcn_mfma_f32_16x16x32_bf16(
              al[mi], bh[ni], acc[mi][ni], 0, 0, 0);
      }
    k0 = kn;
    if (k0 >= kend) break;
  }

  // D row = quad*4 + reg, col = l16 (m89/m91 layout)
  float* Cp = (KS > 1) ? Cf + (size_t)blockIdx.z * M * N : Cf;
#pragma unroll
  for (int mi = 0; mi < MT; ++mi) {
#pragma unroll
    for (int ni = 0; ni < NT; ++ni) {
      int row = bm0 + wm0 + mi * 16 + quad * 4;
      int col = bn0 + wn0 + ni * 16 + l16;
      float bv = BIAS ? bias[col] : 0.f;
#pragma unroll
      for (int r = 0; r < 4; ++r) {
        float v = acc[mi][ni][r] + bv;
        if (RELU) v = fmaxf(v, 0.f);
        size_t o = (size_t)(row + r) * N + col;
        if (OUT_BF16) {
          Chi[o] = f2bf(v);
        } else {
          Cp[o] = v;
        }
      }
    }
  }
}

// ---------------------------------------------------------------------------
// Split-K reduce: sum KS fp32 partials, +bias, relu, round to bf16.
// ---------------------------------------------------------------------------
template <int KS>
__global__ void reduce_split_ks(const float* __restrict__ P,
                                const float* __restrict__ bias,
                                u16* __restrict__ Chi, int M, int N) {
  int i = blockIdx.x * 256 + threadIdx.x;
  int total = (M * N) >> 2;
  if (i >= total) return;
  f32x4 s = ((const f32x4*)P)[i];
#pragma unroll
  for (int z = 1; z < KS; ++z) s += ((const f32x4*)P)[(size_t)z * total + i];
  int col = (i * 4) % N;
  f32x4 bv = *(const f32x4*)(bias + col);
  u16x4 h;
#pragma unroll
  for (int e = 0; e < 4; ++e) h[e] = f2bf(fmaxf(s[e] + bv[e], 0.f));
  *(u16x4*)&Chi[i * 4] = h;
}

// ---------------------------------------------------------------------------
// r2c reduce fused with classifier: h = relu(P0+P1+bias) per row (768),
// out[row] = h @ cls_w + cls_b. One wave per row.
// ---------------------------------------------------------------------------
__global__ void reduce_cls(const float* __restrict__ P,
                           const float* __restrict__ bias,
                           const float* __restrict__ clsw,
                           const float* __restrict__ clsb,
                           float* __restrict__ out) {
  int row = blockIdx.x * 4 + (threadIdx.x >> 6);
  int lane = threadIdx.x & 63;
  const f32x4* p0 = (const f32x4*)(P + (size_t)row * CDIM);
  const f32x4* p1 = (const f32x4*)(P + (size_t)BATCH * CDIM + (size_t)row * CDIM);
  float s0 = 0.f, s1 = 0.f;
#pragma unroll
  for (int i = 0; i < 3; ++i) {
    int c4 = lane + 64 * i;
    f32x4 a = p0[c4] + p1[c4];
    f32x4 bv = *(const f32x4*)(bias + c4 * 4);
#pragma unroll
    for (int e = 0; e < 4; ++e) {
      float h = fmaxf(a[e] + bv[e], 0.f);
      int c = c4 * 4 + e;
      s0 = fmaf(h, clsw[c * 2 + 0], s0);
      s1 = fmaf(h, clsw[c * 2 + 1], s1);
    }
  }
#pragma unroll
  for (int m = 32; m; m >>= 1) {
    s0 += __shfl_xor(s0, m);
    s1 += __shfl_xor(s1, m);
  }
  if (lane == 0) {
    out[row * 2 + 0] = s0 + clsb[0];
    out[row * 2 + 1] = s1 + clsb[1];
  }
}

// ---------------------------------------------------------------------------
// Multi-matrix weight transpose: W fp32 [K][N] -> bf16 [N][Kpad].
// ---------------------------------------------------------------------------
struct TDesc {
  const float* W;
  u16* Th;
  u16* Tl;
  int K, N, Kpad, start;
};
struct TPack { TDesc d[7]; };

__global__ void multi_transpose(TPack p) {
  __shared__ float tile[32][33];
  int b = blockIdx.x;
  int mi = 0;
#pragma unroll
  for (int i = 1; i < 7; ++i)
    if (b >= p.d[i].start) mi = i;
  TDesc dd = p.d[mi];
  int rel = b - dd.start;
  int tilesX = dd.Kpad / 32;
  int k0 = (rel % tilesX) * 32, n0 = (rel / tilesX) * 32;
  int tx = threadIdx.x, ty = threadIdx.y;
#pragma unroll
  for (int i = 0; i < 4; ++i) {
    int k = k0 + ty + 8 * i, n = n0 + tx;
    tile[ty + 8 * i][tx] = (k < dd.K && n < dd.N) ? dd.W[(size_t)k * dd.N + n] : 0.f;
  }
  __syncthreads();
#pragma unroll
  for (int i = 0; i < 4; ++i) {
    int n = n0 + ty + 8 * i, k = k0 + tx;
    if (n < dd.N) {
      uint32_t pk = split2p(tile[tx][ty + 8 * i]);
      dd.Th[(size_t)n * dd.Kpad + k] = (u16)(pk >> 16);
      if (dd.Tl) dd.Tl[(size_t)n * dd.Kpad + k] = (u16)(pk & 0xffffu);
    }
  }
}

// ---------------------------------------------------------------------------
// wsv[k] = sum_c W_src[k,c]*a_src[c] ; wdv[k] = sum_c W_dst[k,c]*a_dst[c]
// ---------------------------------------------------------------------------
__global__ void wvec_kernel(const float* __restrict__ Wsrc,
                            const float* __restrict__ Wdst,
                            const float* __restrict__ a_s,
                            const float* __restrict__ a_d,
                            float* __restrict__ wsv, float* __restrict__ wdv) {
  int k = blockIdx.x;
  int t = threadIdx.x;
  __shared__ float rs[256], rd[256];
  float s = 0.f, d = 0.f;
  for (int c = t; c < CDIM; c += 256) {
    s += Wsrc[(size_t)k * CDIM + c] * a_s[c];
    d += Wdst[(size_t)k * CDIM + c] * a_d[c];
  }
  rs[t] = s; rd[t] = d;
  __syncthreads();
  for (int st = 128; st; st >>= 1) {
    if (t < st) { rs[t] += rs[t + st]; rd[t] += rd[t + st]; }
    __syncthreads();
  }
  if (t == 0) { wsv[k] = rs[0]; wdv[k] = rd[0]; }
}

// es[row] = x[row].wsv ; ed[row] = x[row].wdv — one wave per row, float4.
__global__ void esed_kernel(const float* __restrict__ x,
                            const float* __restrict__ wsv,
                            const float* __restrict__ wdv,
                            float* __restrict__ es, float* __restrict__ ed) {
  int i = blockIdx.x * 256 + threadIdx.x;  // float4 index
  int lane = threadIdx.x & 63;
  int row = i >> 6;
  int c4 = lane * 4;
  f32x4 v = ((const f32x4*)x)[i];
  f32x4 ws = *(const f32x4*)(wsv + c4);
  f32x4 wd = *(const f32x4*)(wdv + c4);
  float a = v[0] * ws[0] + v[1] * ws[1] + v[2] * ws[2] + v[3] * ws[3];
  float b = v[0] * wd[0] + v[1] * wd[1] + v[2] * wd[2] + v[3] * wd[3];
#pragma unroll
  for (int m = 32; m; m >>= 1) {
    a += __shfl_xor(a, m);
    b += __shfl_xor(b, m);
  }
  if (lane == 0) { es[row] = a; ed[row] = b; }
}

// ---------------------------------------------------------------------------
// Fused init: counts=1 (self loop), mask=0, cnt=0.
// ---------------------------------------------------------------------------
__global__ void init_csr(int* counts, int* mask, int* cnt) {
  int i = blockIdx.x * 256 + threadIdx.x;
  if (i < ND) { counts[i] = 1; mask[i] = 0; }
  if (i == 0) *cnt = 0;
}
__global__ void mark_kernel(const int* __restrict__ d1, const int* __restrict__ d2,
                            int* mask) {
  int i = blockIdx.x * 256 + threadIdx.x;
  if (i < BATCH) {
    mask[d1[i]] = 1;
    mask[d2[i]] = 1;
  }
}
__global__ void compact_kernel(const int* __restrict__ mask, int* cnt, int* list) {
  int i = blockIdx.x * 256 + threadIdx.x;
  if (i < ND && mask[i]) {
    int pos = atomicAdd(cnt, 1);
    list[pos] = i;
  }
}

// ---------------------------------------------------------------------------
// CSR build (dst-sorted, self loop at segment head)
// ---------------------------------------------------------------------------
__global__ void count_edges(const int* __restrict__ dst, int* counts) {
  int e = blockIdx.x * 256 + threadIdx.x;
  if (e < E_DD) atomicAdd(&counts[dst[e]], 1);
}
__global__ void scan_kernel(const int* __restrict__ counts, int* __restrict__ offsets) {
  __shared__ int part[512];
  int t = threadIdx.x;
  int base = t * 32;
  int s = 0;
  for (int i = 0; i < 32; ++i) s += counts[base + i];
  part[t] = s;
  __syncthreads();
  if (t == 0) {
    int run = 0;
    for (int i = 0; i < 512; ++i) { int tmp = part[i]; part[i] = run; run += tmp; }
    offsets[ND] = run;
  }
  __syncthreads();
  int run = part[t];
  for (int i = 0; i < 32; ++i) { offsets[base + i] = run; run += counts[base + i]; }
}
__global__ void selfloop_init(const int* __restrict__ offsets, int* cursor, int* slots) {
  int d = blockIdx.x * 256 + threadIdx.x;
  if (d < ND) {
    int o = offsets[d];
    slots[o] = d;
    cursor[d] = o + 1;
  }
}
__global__ void scatter_edges(const int* __restrict__ src, const int* __restrict__ dst,
                              int* cursor, int* slots) {
  int e = blockIdx.x * 256 + threadIdx.x;
  if (e < E_DD) {
    int pos = atomicAdd(&cursor[dst[e]], 1);
    slots[pos] = src[e];
  }
}

// ---------------------------------------------------------------------------
// GAT aggregation over COMPACTED dst list (only nodes feeding the output).
// One wave per dst; shuffle reductions; float4 column loads.
// ---------------------------------------------------------------------------
__global__ __launch_bounds__(256) void gat_aggregate(
    const float* __restrict__ hs, const float* __restrict__ es,
    const float* __restrict__ ed, const int* __restrict__ offsets,
    const int* __restrict__ slots, const float* __restrict__ bias,
    const int* __restrict__ list, const int* __restrict__ cnt,
    float* __restrict__ out) {
  int idx = blockIdx.x * 4 + (threadIdx.x >> 6);
  if (idx >= *cnt) return;
  int d = list[idx];
  int lane = threadIdx.x & 63;
  int beg = offsets[d], end = offsets[d + 1];
  float edv = ed[d];
  float mx = -1e30f;
  for (int j = beg + lane; j < end; j += 64) {
    float e = es[slots[j]] + edv;
    e = e >= 0.f ? e : 0.2f * e;
    mx = fmaxf(mx, e);
  }
#pragma unroll
  for (int m = 32; m; m >>= 1) mx = fmaxf(mx, __shfl_xor(mx, m));
  float sm = 0.f;
  for (int j = beg + lane; j < end; j += 64) {
    float e = es[slots[j]] + edv;
    e = e >= 0.f ? e : 0.2f * e;
    sm += expf(e - mx);
  }
#pragma unroll
  for (int m = 32; m; m >>= 1) sm += __shfl_xor(sm, m);
  float inv = 1.f / (sm + 1e-16f);
  f32x4 a0 = {0.f, 0.f, 0.f, 0.f}, a1 = a0, a2 = a0;
  for (int j = beg; j < end; ++j) {
    int srcn = slots[j];
    float e = es[srcn] + edv;
    e = e >= 0.f ? e : 0.2f * e;
    float alpha = expf(e - mx) * inv;
    const f32x4* hrow = (const f32x4*)(hs + (size_t)srcn * CDIM);
    a0 += alpha * hrow[lane];
    a1 += alpha * hrow[lane + 64];
    a2 += alpha * hrow[lane + 128];
  }
  float* orow = out + (size_t)d * CDIM;
  const f32x4* bv = (const f32x4*)bias;
  f32x4 b0 = bv[lane], b1 = bv[lane + 64], b2 = bv[lane + 128];
  f32x4 o0, o1, o2;
#pragma unroll
  for (int e = 0; e < 4; ++e) {
    o0[e] = fmaxf(a0[e] + b0[e], 0.f);
    o1[e] = fmaxf(a1[e] + b1[e], 0.f);
    o2[e] = fmaxf(a2[e] + b2[e], 0.f);
  }
  ((f32x4*)orow)[lane] = o0;
  ((f32x4*)orow)[lane + 64] = o1;
  ((f32x4*)orow)[lane + 128] = o2;
}

// ---------------------------------------------------------------------------
// cell l2norm -> bf16 [BATCH][Lp], zero pad L..Lp
// ---------------------------------------------------------------------------
__global__ void l2norm_bf16(const float* __restrict__ in, u16* __restrict__ hi,
                            int L, int Lp) {
  int row = blockIdx.x;
  int t = threadIdx.x;
  __shared__ float red[256];
  const float* irow = in + (size_t)row * L;
  float s = 0.f;
  for (int c = t; c < L; c += 256) { float v = irow[c]; s += v * v; }
  red[t] = s;
  __syncthreads();
  for (int st = 128; st; st >>= 1) {
    if (t < st) red[t] += red[t + st];
    __syncthreads();
  }
  float inv = 1.f / fmaxf(sqrtf(red[0]), 1e-12f);
  for (int c = t; c < Lp; c += 256) {
    float v = (c < L) ? irow[c] * inv : 0.f;
    hi[(size_t)row * Lp + c] = f2bf(v);
  }
}

// hidden = l2norm(concat(drug[d1], drug[d2], cell3)) -> bf16 [B][3072]
__global__ __launch_bounds__(256) void hidden_build_bf16(
    const float* __restrict__ drug, const float* __restrict__ c3,
    const int* __restrict__ d1, const int* __restrict__ d2,
    u16* __restrict__ hhi) {
  int row = blockIdx.x;
  int t = threadIdx.x;
  const float* s1 = drug + (size_t)d1[row] * CDIM;
  const float* s2 = drug + (size_t)d2[row] * CDIM;
  const float* s3 = c3 + (size_t)row * (2 * CDIM);
  float vals[12];
  float ss = 0.f;
#pragma unroll
  for (int i = 0; i < 12; ++i) {
    int c = t + 256 * i;
    float v;
    if (i < 3)      v = s1[c];
    else if (i < 6) v = s2[c - CDIM];
    else            v = s3[c - 2 * CDIM];
    vals[i] = v;
    ss += v * v;
  }
  __shared__ float red[256];
  red[t] = ss;
  __syncthreads();
  for (int st = 128; st; st >>= 1) {
    if (t < st) red[t] += red[t + st];
    __syncthreads();
  }
  float inv = 1.f / fmaxf(sqrtf(red[0]), 1e-12f);
  u16* hrow_h = hhi + (size_t)row * (4 * CDIM);
#pragma unroll
  for (int i = 0; i < 12; ++i) hrow_h[t + 256 * i] = f2bf(vals[i] * inv);
}

// ---------------------------------------------------------------------------
extern "C" void kernel_launch(void* const* d_in, const int* in_sizes, int n_in,
                              void* d_out, int out_size, void* d_ws, size_t ws_size,
                              hipStream_t stream) {
  const float* x_drug   = (const float*)d_in[0];
  const float* cellf    = (const float*)d_in[2];
  const float* W_src_dd = (const float*)d_in[3];
  const float* W_dst_dd = (const float*)d_in[4];
  const float* a_src_dd = (const float*)d_in[5];
  const float* a_dst_dd = (const float*)d_in[6];
  const float* b_dd     = (const float*)d_in[7];
  const float* red1_w = (const float*)d_in[18];
  const float* red1_b = (const float*)d_in[19];
  const float* red2_w = (const float*)d_in[20];
  const float* red2_b = (const float*)d_in[21];
  const float* red3_w = (const float*)d_in[22];
  const float* red3_b = (const float*)d_in[23];
  const float* r2a_w  = (const float*)d_in[24];
  const float* r2a_b  = (const float*)d_in[25];
  const float* r2b_w  = (const float*)d_in[26];
  const float* r2b_b  = (const float*)d_in[27];
  const float* r2c_w  = (const float*)d_in[28];
  const float* r2c_b  = (const float*)d_in[29];
  const float* cls_w  = (const float*)d_in[30];
  const float* cls_b  = (const float*)d_in[31];
  const int* drug1_id = (const int*)d_in[32];
  const int* drug2_id = (const int*)d_in[33];
  const int* ei_dd    = (const int*)d_in[34];
  float* out = (float*)d_out;

  const int* dd_src = ei_dd;
  const int* dd_dst = ei_dd + E_DD;

  char* w = (char*)d_ws;
  size_t off = 0;
  auto alloc = [&](size_t bytes) -> char* {
    char* p = w + off;
    off = (off + bytes + 255) & ~(size_t)255;
    return p;
  };
  // fp32 buffers
  float* hs   = (float*)alloc((size_t)ND * CDIM * 4);        // reused as hidden bf16
  float* drug = (float*)alloc((size_t)ND * CDIM * 4);
  float* c3   = (float*)alloc((size_t)BATCH * 2 * CDIM * 4);
  float* P    = (float*)alloc((size_t)2 * BATCH * 2048 * 4); // split-K partials, 67 MB
  u16* hid_hi = (u16*)hs;                                    // hs dead after GAT
  // bf16 activations (single array each — consumed as 1-term A)
  u16* cn_hi = (u16*)alloc((size_t)BATCH * 896 * 2);
  u16* c1_hi = (u16*)alloc((size_t)BATCH * 2048 * 2);        // shared with h1
  u16* c2_hi = (u16*)alloc((size_t)BATCH * 512 * 2);         // shared with h2
  // transposed weights [N][Kpad] — all single bf16 now
  u16* wsrcT_hi = (u16*)alloc((size_t)CDIM * FD * 2);
  u16* r1T_hi = (u16*)alloc((size_t)2048 * 896 * 2);
  u16* r2T_hi = (u16*)alloc((size_t)512 * 2048 * 2);
  u16* r3T_hi = (u16*)alloc((size_t)1536 * 512 * 2);
  u16* raT_hi = (u16*)alloc((size_t)2048 * 3072 * 2);
  u16* rbT_hi = (u16*)alloc((size_t)512 * 2048 * 2);
  u16* rcT_hi = (u16*)alloc((size_t)768 * 512 * 2);
  // GAT scalars / CSR / dst-compaction
  float* es  = (float*)alloc((size_t)ND * 4);
  float* ed  = (float*)alloc((size_t)ND * 4);
  float* wsv = (float*)alloc(FD * 4);
  float* wdv = (float*)alloc(FD * 4);
  int* counts  = (int*)alloc((size_t)ND * 4);
  int* offsets = (int*)alloc((size_t)(ND + 1) * 4);
  int* cursor  = (int*)alloc((size_t)ND * 4);
  int* slots   = (int*)alloc((size_t)(E_DD + ND) * 4);
  int* mask    = (int*)alloc((size_t)ND * 4);
  int* list    = (int*)alloc((size_t)ND * 4);
  int* cnt     = (int*)alloc(256);
  (void)ws_size; (void)n_in; (void)in_sizes; (void)out_size;

  // --- weight prep: 7 transposes in one launch (all single-bf16) ---
  TPack tp;
  tp.d[0] = {W_src_dd, wsrcT_hi, nullptr, 256, 768, 256, 0};
  tp.d[1] = {red1_w, r1T_hi, nullptr, 890, 2048, 896, 192};
  tp.d[2] = {red2_w, r2T_hi, nullptr, 2048, 512, 2048, 1984};
  tp.d[3] = {red3_w, r3T_hi, nullptr, 512, 1536, 512, 3008};
  tp.d[4] = {r2a_w, raT_hi, nullptr, 3072, 2048, 3072, 3776};
  tp.d[5] = {r2b_w, rbT_hi, nullptr, 2048, 512, 2048, 9920};
  tp.d[6] = {r2c_w, rcT_hi, nullptr, 512, 768, 512, 10944};
  multi_transpose<<<11328, dim3(32, 8), 0, stream>>>(tp);

  // --- GAT scalar prep + needed-dst compaction ---
  wvec_kernel<<<FD, 256, 0, stream>>>(W_src_dd, W_dst_dd, a_src_dd, a_dst_dd, wsv, wdv);
  esed_kernel<<<ND * FD / 1024, 256, 0, stream>>>(x_drug, wsv, wdv, es, ed);
  init_csr<<<ND / 256, 256, 0, stream>>>(counts, mask, cnt);
  mark_kernel<<<BATCH / 256, 256, 0, stream>>>(drug1_id, drug2_id, mask);
  compact_kernel<<<ND / 256, 256, 0, stream>>>(mask, cnt, list);

  // --- cell MLP (pure bf16: validated error ladder) ---
  l2norm_bf16<<<BATCH, 256, 0, stream>>>(cellf, cn_hi, 890, 896);
  mfma_gemm<1, 1, 1, 1, 0, 0, 0><<<dim3(BATCH / 128, 2048 / 128), 256, 0, stream>>>(
      nullptr, cn_hi, nullptr, r1T_hi, nullptr, red1_b, nullptr, c1_hi, BATCH, 2048, 896);
  mfma_gemm<4, 0, 0, 0, 0, 0, 0><<<dim3(BATCH / 128, 512 / 128, 4), 256, 0, stream>>>(
      nullptr, c1_hi, nullptr, r2T_hi, nullptr, nullptr, P, nullptr, BATCH, 512, 2048);
  reduce_split_ks<4><<<BATCH * 512 / 1024, 256, 0, stream>>>(P, red2_b, c2_hi, BATCH, 512);
  mfma_gemm<1, 0, 1, 1, 0, 0, 0><<<dim3(BATCH / 128, 1536 / 128), 256, 0, stream>>>(
      nullptr, c2_hi, nullptr, r3T_hi, nullptr, red3_b, c3, nullptr, BATCH, 1536, 512);

  // --- GAT (bf16x2: exact-A x rounded-B; downstream l2norm removes scale) ---
  mfma_gemm<1, 0, 0, 0, 1, 1, 0><<<dim3(ND / 128, CDIM / 128), 256, 0, stream>>>(
      x_drug, nullptr, nullptr, wsrcT_hi, nullptr, nullptr, hs, nullptr, ND, CDIM, FD);
  count_edges<<<E_DD / 256, 256, 0, stream>>>(dd_dst, counts);
  scan_kernel<<<1, 512, 0, stream>>>(counts, offsets);
  selfloop_init<<<ND / 256, 256, 0, stream>>>(offsets, cursor, slots);
  scatter_edges<<<E_DD / 256, 256, 0, stream>>>(dd_src, dd_dst, cursor, slots);
  gat_aggregate<<<ND / 4, 256, 0, stream>>>(hs, es, ed, offsets, slots, b_dd, list, cnt, drug);

  // --- gather + concat + l2norm -> bf16 (hidden aliases hs; last read of drug) ---
  hidden_build_bf16<<<BATCH, 256, 0, stream>>>(drug, c3, drug1_id, drug2_id, hid_hi);

  // --- head MLP, pure bf16; r2a split-K=2 for 4 blocks/CU ---
  mfma_gemm<2, 0, 0, 0, 0, 0, 0><<<dim3(BATCH / 128, 2048 / 128, 2), 256, 0, stream>>>(
      nullptr, hid_hi, nullptr, raT_hi, nullptr, nullptr, P, nullptr, BATCH, 2048, 3072);
  reduce_split_ks<2><<<BATCH * 2048 / 1024, 256, 0, stream>>>(P, r2a_b, c1_hi, BATCH, 2048);
  mfma_gemm<4, 0, 0, 0, 0, 0, 0><<<dim3(BATCH / 128, 512 / 128, 4), 256, 0, stream>>>(
      nullptr, c1_hi, nullptr, rbT_hi, nullptr, nullptr, P, nullptr, BATCH, 512, 2048);
  reduce_split_ks<4><<<BATCH * 512 / 1024, 256, 0, stream>>>(P, r2b_b, c2_hi, BATCH, 512);
  mfma_gemm<2, 0, 0, 0, 0, 0, 0><<<dim3(BATCH / 128, CDIM / 128, 2), 256, 0, stream>>>(
      nullptr, c2_hi, nullptr, rcT_hi, nullptr, nullptr, P, nullptr, BATCH, CDIM, 512);
  reduce_cls<<<BATCH / 4, 256, 0, stream>>>(P, r2c_b, cls_w, cls_b, out);
}

// Round 12
// 491.857 us; speedup vs baseline: 1.0339x; 1.0339x over previous
//
#include <hip/hip_runtime.h>
#include <cstdint>

#define ND 16384
#define BATCH 4096
#define CDIM 768
#define E_DD 131072
#define FD 256

typedef unsigned short u16;
typedef u16 u16x4 __attribute__((ext_vector_type(4)));
typedef u16 u16x8 __attribute__((ext_vector_type(8)));
typedef short s16x8 __attribute__((ext_vector_type(8)));
typedef float f32x4 __attribute__((ext_vector_type(4)));

__device__ __forceinline__ u16 f2bf(float x) {
  union { float f; uint32_t u; } v; v.f = x;
  uint32_t r = v.u + 0x7fffu + ((v.u >> 16) & 1u);
  return (u16)(r >> 16);
}
__device__ __forceinline__ float bf2f(u16 h) {
  union { float f; uint32_t u; } v; v.u = ((uint32_t)h) << 16;
  return v.f;
}
// (hi << 16) | lo ; hi = bf16(x), lo = bf16(x - hi)
__device__ __forceinline__ uint32_t split2p(float x) {
  u16 h = f2bf(x);
  u16 l = f2bf(x - bf2f(h));
  return ((uint32_t)h << 16) | l;
}

// ---------------------------------------------------------------------------
// MFMA GEMM, 128x128 tile, BK=32, 4 waves (2x2), MT=NT=4, 16x16x32 bf16.
// R5-proven core: coalesced staging (4 threads/row cover 64B), KP=40 pitch.
// ALO/BLO: hi+lo error-compensation terms. ASPLIT: fp32 A split on load.
// OUT_BF16: epilogue writes round-to-nearest bf16.
// KS>1: split-K partial mode — blockIdx.z K-chunk, partial at Cf + z*M*N.
// NOTE (R11 post-mortem): split-K on the big r2a shape regressed — fp32
// partial traffic (4x output bytes) outweighs the occupancy gain. KS=1 there.
// ---------------------------------------------------------------------------
#define KP 40

template <int KS, int OUT_BF16, int RELU, int BIAS, int ASPLIT, int ALO, int BLO>
__global__ __launch_bounds__(256) void mfma_gemm(
    const float* __restrict__ Af,
    const u16* __restrict__ Ahi, const u16* __restrict__ Alo,
    const u16* __restrict__ Bhi, const u16* __restrict__ Blo,
    const float* __restrict__ bias,
    float* __restrict__ Cf, u16* __restrict__ Chi,
    int M, int N, int K) {
  constexpr int MT = 4, NT = 4;
  constexpr int BM = 128, BN = 128;
  constexpr int ASEG = BM / 64;
  constexpr int BSEG = BN / 64;
  constexpr int AARR = ALO ? 2 : 1;
  constexpr int BARR = BLO ? 2 : 1;
  __shared__ __align__(16) u16 As[AARR][BM][KP];
  __shared__ __align__(16) u16 Bs[BARR][BN][KP];

  const int t = threadIdx.x;
  const int bm0 = blockIdx.x * BM, bn0 = blockIdx.y * BN;
  const int wid = t >> 6, lane = t & 63;
  const int quad = lane >> 4, l16 = lane & 15;
  const int wm0 = (wid >> 1) * (MT * 16);
  const int wn0 = (wid & 1) * (NT * 16);

  const int chunk = K / KS;
  const int kbeg = (KS > 1) ? (int)blockIdx.z * chunk : 0;
  const int kend = kbeg + chunk;

  f32x4 acc[MT][NT];
#pragma unroll
  for (int i = 0; i < MT; ++i)
#pragma unroll
    for (int j = 0; j < NT; ++j) acc[i][j] = (f32x4){0.f, 0.f, 0.f, 0.f};

  u16x8 pAh[ASEG], pAl[ASEG], pBh[BSEG], pBl[BSEG];

  auto loadA = [&](int c, int kk) {
    int s = t + 256 * c, row = s >> 2, kq = (s & 3) * 8;
    size_t off = (size_t)(bm0 + row) * K + kk + kq;
    if (ASPLIT) {
      f32x4 v0 = *(const f32x4*)(Af + off);
      f32x4 v1 = *(const f32x4*)(Af + off + 4);
      u16x8 h, l;
#pragma unroll
      for (int e = 0; e < 4; ++e) {
        uint32_t p = split2p(v0[e]);
        h[e] = (u16)(p >> 16); l[e] = (u16)(p & 0xffffu);
        uint32_t q = split2p(v1[e]);
        h[e + 4] = (u16)(q >> 16); l[e + 4] = (u16)(q & 0xffffu);
      }
      pAh[c] = h; pAl[c] = l;
    } else {
      pAh[c] = *(const u16x8*)(Ahi + off);
      if (ALO) pAl[c] = *(const u16x8*)(Alo + off);
    }
  };
  auto loadB = [&](int c, int kk) {
    int s = t + 256 * c, row = s >> 2, kq = (s & 3) * 8;
    size_t off = (size_t)(bn0 + row) * K + kk + kq;
    pBh[c] = *(const u16x8*)(Bhi + off);
    if (BLO) pBl[c] = *(const u16x8*)(Blo + off);
  };

#pragma unroll
  for (int c = 0; c < ASEG; ++c) loadA(c, kbeg);
#pragma unroll
  for (int c = 0; c < BSEG; ++c) loadB(c, kbeg);

  for (int k0 = kbeg;;) {
    __syncthreads();
#pragma unroll
    for (int c = 0; c < ASEG; ++c) {
      int s = t + 256 * c, row = s >> 2, kq = (s & 3) * 8;
      *(u16x8*)&As[0][row][kq] = pAh[c];
      if (ALO) *(u16x8*)&As[AARR - 1][row][kq] = pAl[c];
    }
#pragma unroll
    for (int c = 0; c < BSEG; ++c) {
      int s = t + 256 * c, row = s >> 2, kq = (s & 3) * 8;
      *(u16x8*)&Bs[0][row][kq] = pBh[c];
      if (BLO) *(u16x8*)&Bs[BARR - 1][row][kq] = pBl[c];
    }
    __syncthreads();

    int kn = k0 + 32;
    if (kn < kend) {
#pragma unroll
      for (int c = 0; c < ASEG; ++c) loadA(c, kn);
#pragma unroll
      for (int c = 0; c < BSEG; ++c) loadB(c, kn);
    }

    s16x8 ah[MT], al[MT], bh[NT], bl[NT];
#pragma unroll
    for (int mi = 0; mi < MT; ++mi) {
      ah[mi] = *(const s16x8*)&As[0][wm0 + mi * 16 + l16][quad * 8];
      if (ALO) al[mi] = *(const s16x8*)&As[AARR - 1][wm0 + mi * 16 + l16][quad * 8];
    }
#pragma unroll
    for (int ni = 0; ni < NT; ++ni) {
      bh[ni] = *(const s16x8*)&Bs[0][wn0 + ni * 16 + l16][quad * 8];
      if (BLO) bl[ni] = *(const s16x8*)&Bs[BARR - 1][wn0 + ni * 16 + l16][quad * 8];
    }
#pragma unroll
    for (int mi = 0; mi < MT; ++mi)
#pragma unroll
      for (int ni = 0; ni < NT; ++ni) {
        acc[mi][ni] = __builtin_amdgcn_mfma_f32_16x16x32_bf16(
            ah[mi], bh[ni], acc[mi][ni], 0, 0, 0);
        if (BLO)
          acc[mi][ni] = __builtin_amdgcn_mfma_f32_16x16x32_bf16(
              ah[mi], bl[ni], acc[mi][ni], 0, 0, 0);
        if (ALO)
          acc[mi][ni] = __builtin_amdgcn_mfma_f32_16x16x32_bf16(
              al[mi], bh[ni], acc[mi][ni], 0, 0, 0);
      }
    k0 = kn;
    if (k0 >= kend) break;
  }

  // D row = quad*4 + reg, col = l16 (m89/m91 layout)
  float* Cp = (KS > 1) ? Cf + (size_t)blockIdx.z * M * N : Cf;
#pragma unroll
  for (int mi = 0; mi < MT; ++mi) {
#pragma unroll
    for (int ni = 0; ni < NT; ++ni) {
      int row = bm0 + wm0 + mi * 16 + quad * 4;
      int col = bn0 + wn0 + ni * 16 + l16;
      float bv = BIAS ? bias[col] : 0.f;
#pragma unroll
      for (int r = 0; r < 4; ++r) {
        float v = acc[mi][ni][r] + bv;
        if (RELU) v = fmaxf(v, 0.f);
        size_t o = (size_t)(row + r) * N + col;
        if (OUT_BF16) {
          Chi[o] = f2bf(v);
        } else {
          Cp[o] = v;
        }
      }
    }
  }
}

// ---------------------------------------------------------------------------
// Split-K reduce: sum KS fp32 partials, +bias, relu, round to bf16.
// ---------------------------------------------------------------------------
template <int KS>
__global__ void reduce_split_ks(const float* __restrict__ P,
                                const float* __restrict__ bias,
                                u16* __restrict__ Chi, int M, int N) {
  int i = blockIdx.x * 256 + threadIdx.x;
  int total = (M * N) >> 2;
  if (i >= total) return;
  f32x4 s = ((const f32x4*)P)[i];
#pragma unroll
  for (int z = 1; z < KS; ++z) s += ((const f32x4*)P)[(size_t)z * total + i];
  int col = (i * 4) % N;
  f32x4 bv = *(const f32x4*)(bias + col);
  u16x4 h;
#pragma unroll
  for (int e = 0; e < 4; ++e) h[e] = f2bf(fmaxf(s[e] + bv[e], 0.f));
  *(u16x4*)&Chi[i * 4] = h;
}

// ---------------------------------------------------------------------------
// r2c reduce fused with classifier: h = relu(P0+P1+bias) per row (768),
// out[row] = h @ cls_w + cls_b. One wave per row.
// ---------------------------------------------------------------------------
__global__ void reduce_cls(const float* __restrict__ P,
                           const float* __restrict__ bias,
                           const float* __restrict__ clsw,
                           const float* __restrict__ clsb,
                           float* __restrict__ out) {
  int row = blockIdx.x * 4 + (threadIdx.x >> 6);
  int lane = threadIdx.x & 63;
  const f32x4* p0 = (const f32x4*)(P + (size_t)row * CDIM);
  const f32x4* p1 = (const f32x4*)(P + (size_t)BATCH * CDIM + (size_t)row * CDIM);
  float s0 = 0.f, s1 = 0.f;
#pragma unroll
  for (int i = 0; i < 3; ++i) {
    int c4 = lane + 64 * i;
    f32x4 a = p0[c4] + p1[c4];
    f32x4 bv = *(const f32x4*)(bias + c4 * 4);
#pragma unroll
    for (int e = 0; e < 4; ++e) {
      float h = fmaxf(a[e] + bv[e], 0.f);
      int c = c4 * 4 + e;
      s0 = fmaf(h, clsw[c * 2 + 0], s0);
      s1 = fmaf(h, clsw[c * 2 + 1], s1);
    }
  }
#pragma unroll
  for (int m = 32; m; m >>= 1) {
    s0 += __shfl_xor(s0, m);
    s1 += __shfl_xor(s1, m);
  }
  if (lane == 0) {
    out[row * 2 + 0] = s0 + clsb[0];
    out[row * 2 + 1] = s1 + clsb[1];
  }
}

// ---------------------------------------------------------------------------
// Multi-matrix weight transpose: W fp32 [K][N] -> bf16 [N][Kpad].
// ---------------------------------------------------------------------------
struct TDesc {
  const float* W;
  u16* Th;
  int K, N, Kpad, start;
};
struct TPack { TDesc d[7]; };

__global__ void multi_transpose(TPack p) {
  __shared__ float tile[32][33];
  int b = blockIdx.x;
  int mi = 0;
#pragma unroll
  for (int i = 1; i < 7; ++i)
    if (b >= p.d[i].start) mi = i;
  TDesc dd = p.d[mi];
  int rel = b - dd.start;
  int tilesX = dd.Kpad / 32;
  int k0 = (rel % tilesX) * 32, n0 = (rel / tilesX) * 32;
  int tx = threadIdx.x, ty = threadIdx.y;
#pragma unroll
  for (int i = 0; i < 4; ++i) {
    int k = k0 + ty + 8 * i, n = n0 + tx;
    tile[ty + 8 * i][tx] = (k < dd.K && n < dd.N) ? dd.W[(size_t)k * dd.N + n] : 0.f;
  }
  __syncthreads();
#pragma unroll
  for (int i = 0; i < 4; ++i) {
    int n = n0 + ty + 8 * i, k = k0 + tx;
    if (n < dd.N) dd.Th[(size_t)n * dd.Kpad + k] = f2bf(tile[tx][ty + 8 * i]);
  }
}

// ---------------------------------------------------------------------------
// wsv[k] = sum_c W_src[k,c]*a_src[c] ; wdv[k] = sum_c W_dst[k,c]*a_dst[c]
// ---------------------------------------------------------------------------
__global__ void wvec_kernel(const float* __restrict__ Wsrc,
                            const float* __restrict__ Wdst,
                            const float* __restrict__ a_s,
                            const float* __restrict__ a_d,
                            float* __restrict__ wsv, float* __restrict__ wdv) {
  int k = blockIdx.x;
  int t = threadIdx.x;
  __shared__ float rs[256], rd[256];
  float s = 0.f, d = 0.f;
  for (int c = t; c < CDIM; c += 256) {
    s += Wsrc[(size_t)k * CDIM + c] * a_s[c];
    d += Wdst[(size_t)k * CDIM + c] * a_d[c];
  }
  rs[t] = s; rd[t] = d;
  __syncthreads();
  for (int st = 128; st; st >>= 1) {
    if (t < st) { rs[t] += rs[t + st]; rd[t] += rd[t + st]; }
    __syncthreads();
  }
  if (t == 0) { wsv[k] = rs[0]; wdv[k] = rd[0]; }
}

// es[row] = x[row].wsv ; ed[row] = x[row].wdv — one wave per row, float4.
__global__ void esed_kernel(const float* __restrict__ x,
                            const float* __restrict__ wsv,
                            const float* __restrict__ wdv,
                            float* __restrict__ es, float* __restrict__ ed) {
  int i = blockIdx.x * 256 + threadIdx.x;  // float4 index
  int lane = threadIdx.x & 63;
  int row = i >> 6;
  int c4 = lane * 4;
  f32x4 v = ((const f32x4*)x)[i];
  f32x4 ws = *(const f32x4*)(wsv + c4);
  f32x4 wd = *(const f32x4*)(wdv + c4);
  float a = v[0] * ws[0] + v[1] * ws[1] + v[2] * ws[2] + v[3] * ws[3];
  float b = v[0] * wd[0] + v[1] * wd[1] + v[2] * wd[2] + v[3] * wd[3];
#pragma unroll
  for (int m = 32; m; m >>= 1) {
    a += __shfl_xor(a, m);
    b += __shfl_xor(b, m);
  }
  if (lane == 0) { es[row] = a; ed[row] = b; }
}

// ---------------------------------------------------------------------------
// Fused init: counts=1 (self loop), mask=0, cnt=0.
// ---------------------------------------------------------------------------
__global__ void init_csr(int* counts, int* mask, int* cnt) {
  int i = blockIdx.x * 256 + threadIdx.x;
  if (i < ND) { counts[i] = 1; mask[i] = 0; }
  if (i == 0) *cnt = 0;
}
__global__ void mark_kernel(const int* __restrict__ d1, const int* __restrict__ d2,
                            int* mask) {
  int i = blockIdx.x * 256 + threadIdx.x;
  if (i < BATCH) {
    mask[d1[i]] = 1;
    mask[d2[i]] = 1;
  }
}
__global__ void compact_kernel(const int* __restrict__ mask, int* cnt, int* list) {
  int i = blockIdx.x * 256 + threadIdx.x;
  if (i < ND && mask[i]) {
    int pos = atomicAdd(cnt, 1);
    list[pos] = i;
  }
}

// ---------------------------------------------------------------------------
// CSR build (dst-sorted, self loop at segment head)
// ---------------------------------------------------------------------------
__global__ void count_edges(const int* __restrict__ dst, int* counts) {
  int e = blockIdx.x * 256 + threadIdx.x;
  if (e < E_DD) atomicAdd(&counts[dst[e]], 1);
}
// scan + self-loop head placement + cursor init, fused (single block).
__global__ void scan_kernel(const int* __restrict__ counts, int* __restrict__ offsets,
                            int* __restrict__ cursor, int* __restrict__ slots) {
  __shared__ int part[512];
  int t = threadIdx.x;
  int base = t * 32;
  int s = 0;
  for (int i = 0; i < 32; ++i) s += counts[base + i];
  part[t] = s;
  __syncthreads();
  if (t == 0) {
    int run = 0;
    for (int i = 0; i < 512; ++i) { int tmp = part[i]; part[i] = run; run += tmp; }
    offsets[ND] = run;
  }
  __syncthreads();
  int run = part[t];
  for (int i = 0; i < 32; ++i) {
    int d = base + i;
    offsets[d] = run;
    slots[run] = d;        // self loop at segment head
    cursor[d] = run + 1;
    run += counts[d];
  }
}
__global__ void scatter_edges(const int* __restrict__ src, const int* __restrict__ dst,
                              int* cursor, int* slots) {
  int e = blockIdx.x * 256 + threadIdx.x;
  if (e < E_DD) {
    int pos = atomicAdd(&cursor[dst[e]], 1);
    slots[pos] = src[e];
  }
}

// ---------------------------------------------------------------------------
// GAT aggregation over COMPACTED dst list. One wave per dst; shuffle
// reductions; hs and output are bf16 (validated error ladder — both are
// re-rounded downstream anyway).
// ---------------------------------------------------------------------------
__global__ __launch_bounds__(256) void gat_aggregate(
    const u16* __restrict__ hs, const float* __restrict__ es,
    const float* __restrict__ ed, const int* __restrict__ offsets,
    const int* __restrict__ slots, const float* __restrict__ bias,
    const int* __restrict__ list, const int* __restrict__ cnt,
    u16* __restrict__ out) {
  int idx = blockIdx.x * 4 + (threadIdx.x >> 6);
  if (idx >= *cnt) return;
  int d = list[idx];
  int lane = threadIdx.x & 63;
  int beg = offsets[d], end = offsets[d + 1];
  float edv = ed[d];
  float mx = -1e30f;
  for (int j = beg + lane; j < end; j += 64) {
    float e = es[slots[j]] + edv;
    e = e >= 0.f ? e : 0.2f * e;
    mx = fmaxf(mx, e);
  }
#pragma unroll
  for (int m = 32; m; m >>= 1) mx = fmaxf(mx, __shfl_xor(mx, m));
  float sm = 0.f;
  for (int j = beg + lane; j < end; j += 64) {
    float e = es[slots[j]] + edv;
    e = e >= 0.f ? e : 0.2f * e;
    sm += expf(e - mx);
  }
#pragma unroll
  for (int m = 32; m; m >>= 1) sm += __shfl_xor(sm, m);
  float inv = 1.f / (sm + 1e-16f);
  f32x4 a0 = {0.f, 0.f, 0.f, 0.f}, a1 = a0, a2 = a0;
  int c4 = lane * 4;
  for (int j = beg; j < end; ++j) {
    int srcn = slots[j];
    float e = es[srcn] + edv;
    e = e >= 0.f ? e : 0.2f * e;
    float alpha = expf(e - mx) * inv;
    const u16* hrow = hs + (size_t)srcn * CDIM;
    u16x4 r0 = *(const u16x4*)(hrow + c4);
    u16x4 r1 = *(const u16x4*)(hrow + 256 + c4);
    u16x4 r2 = *(const u16x4*)(hrow + 512 + c4);
#pragma unroll
    for (int e2 = 0; e2 < 4; ++e2) {
      a0[e2] = fmaf(alpha, bf2f(r0[e2]), a0[e2]);
      a1[e2] = fmaf(alpha, bf2f(r1[e2]), a1[e2]);
      a2[e2] = fmaf(alpha, bf2f(r2[e2]), a2[e2]);
    }
  }
  u16* orow = out + (size_t)d * CDIM;
  u16x4 o0, o1, o2;
#pragma unroll
  for (int e2 = 0; e2 < 4; ++e2) {
    o0[e2] = f2bf(fmaxf(a0[e2] + bias[c4 + e2], 0.f));
    o1[e2] = f2bf(fmaxf(a1[e2] + bias[256 + c4 + e2], 0.f));
    o2[e2] = f2bf(fmaxf(a2[e2] + bias[512 + c4 + e2], 0.f));
  }
  *(u16x4*)(orow + c4) = o0;
  *(u16x4*)(orow + 256 + c4) = o1;
  *(u16x4*)(orow + 512 + c4) = o2;
}

// ---------------------------------------------------------------------------
// cell l2norm -> bf16 [BATCH][Lp], zero pad L..Lp
// ---------------------------------------------------------------------------
__global__ void l2norm_bf16(const float* __restrict__ in, u16* __restrict__ hi,
                            int L, int Lp) {
  int row = blockIdx.x;
  int t = threadIdx.x;
  __shared__ float red[256];
  const float* irow = in + (size_t)row * L;
  float s = 0.f;
  for (int c = t; c < L; c += 256) { float v = irow[c]; s += v * v; }
  red[t] = s;
  __syncthreads();
  for (int st = 128; st; st >>= 1) {
    if (t < st) red[t] += red[t + st];
    __syncthreads();
  }
  float inv = 1.f / fmaxf(sqrtf(red[0]), 1e-12f);
  for (int c = t; c < Lp; c += 256) {
    float v = (c < L) ? irow[c] * inv : 0.f;
    hi[(size_t)row * Lp + c] = f2bf(v);
  }
}

// hidden = l2norm(concat(drug[d1], drug[d2], cell3)) -> bf16 [B][3072]
// drug and c3 are bf16.
__global__ __launch_bounds__(256) void hidden_build_bf16(
    const u16* __restrict__ drug, const u16* __restrict__ c3,
    const int* __restrict__ d1, const int* __restrict__ d2,
    u16* __restrict__ hhi) {
  int row = blockIdx.x;
  int t = threadIdx.x;
  const u16* s1 = drug + (size_t)d1[row] * CDIM;
  const u16* s2 = drug + (size_t)d2[row] * CDIM;
  const u16* s3 = c3 + (size_t)row * (2 * CDIM);
  float vals[12];
  float ss = 0.f;
#pragma unroll
  for (int i = 0; i < 12; ++i) {
    int c = t + 256 * i;
    float v;
    if (i < 3)      v = bf2f(s1[c]);
    else if (i < 6) v = bf2f(s2[c - CDIM]);
    else            v = bf2f(s3[c - 2 * CDIM]);
    vals[i] = v;
    ss += v * v;
  }
  __shared__ float red[256];
  red[t] = ss;
  __syncthreads();
  for (int st = 128; st; st >>= 1) {
    if (t < st) red[t] += red[t + st];
    __syncthreads();
  }
  float inv = 1.f / fmaxf(sqrtf(red[0]), 1e-12f);
  u16* hrow_h = hhi + (size_t)row * (4 * CDIM);
#pragma unroll
  for (int i = 0; i < 12; ++i) hrow_h[t + 256 * i] = f2bf(vals[i] * inv);
}

// ---------------------------------------------------------------------------
extern "C" void kernel_launch(void* const* d_in, const int* in_sizes, int n_in,
                              void* d_out, int out_size, void* d_ws, size_t ws_size,
                              hipStream_t stream) {
  const float* x_drug   = (const float*)d_in[0];
  const float* cellf    = (const float*)d_in[2];
  const float* W_src_dd = (const float*)d_in[3];
  const float* W_dst_dd = (const float*)d_in[4];
  const float* a_src_dd = (const float*)d_in[5];
  const float* a_dst_dd = (const float*)d_in[6];
  const float* b_dd     = (const float*)d_in[7];
  const float* red1_w = (const float*)d_in[18];
  const float* red1_b = (const float*)d_in[19];
  const float* red2_w = (const float*)d_in[20];
  const float* red2_b = (const float*)d_in[21];
  const float* red3_w = (const float*)d_in[22];
  const float* red3_b = (const float*)d_in[23];
  const float* r2a_w  = (const float*)d_in[24];
  const float* r2a_b  = (const float*)d_in[25];
  const float* r2b_w  = (const float*)d_in[26];
  const float* r2b_b  = (const float*)d_in[27];
  const float* r2c_w  = (const float*)d_in[28];
  const float* r2c_b  = (const float*)d_in[29];
  const float* cls_w  = (const float*)d_in[30];
  const float* cls_b  = (const float*)d_in[31];
  const int* drug1_id = (const int*)d_in[32];
  const int* drug2_id = (const int*)d_in[33];
  const int* ei_dd    = (const int*)d_in[34];
  float* out = (float*)d_out;

  const int* dd_src = ei_dd;
  const int* dd_dst = ei_dd + E_DD;

  char* w = (char*)d_ws;
  size_t off = 0;
  auto alloc = [&](size_t bytes) -> char* {
    char* p = w + off;
    off = (off + bytes + 255) & ~(size_t)255;
    return p;
  };
  // bf16 intermediates (all re-rounded downstream; validated error ladder)
  u16* hs   = (u16*)alloc((size_t)ND * CDIM * 2);            // reused as hidden bf16
  u16* drug = (u16*)alloc((size_t)ND * CDIM * 2);
  u16* c3   = (u16*)alloc((size_t)BATCH * 2 * CDIM * 2);
  float* P  = (float*)alloc((size_t)4 * BATCH * 512 * 4);    // split-K partials, 33.5 MB
  u16* hid_hi = hs;  // alias: hs (ND*CDIM) == hidden (BATCH*4*CDIM), same count
  // bf16 activations
  u16* cn_hi = (u16*)alloc((size_t)BATCH * 896 * 2);
  u16* c1_hi = (u16*)alloc((size_t)BATCH * 2048 * 2);        // shared with h1
  u16* c2_hi = (u16*)alloc((size_t)BATCH * 512 * 2);         // shared with h2
  // transposed weights [N][Kpad] — single bf16
  u16* wsrcT_hi = (u16*)alloc((size_t)CDIM * FD * 2);
  u16* r1T_hi = (u16*)alloc((size_t)2048 * 896 * 2);
  u16* r2T_hi = (u16*)alloc((size_t)512 * 2048 * 2);
  u16* r3T_hi = (u16*)alloc((size_t)1536 * 512 * 2);
  u16* raT_hi = (u16*)alloc((size_t)2048 * 3072 * 2);
  u16* rbT_hi = (u16*)alloc((size_t)512 * 2048 * 2);
  u16* rcT_hi = (u16*)alloc((size_t)768 * 512 * 2);
  // GAT scalars / CSR / dst-compaction
  float* es  = (float*)alloc((size_t)ND * 4);
  float* ed  = (float*)alloc((size_t)ND * 4);
  float* wsv = (float*)alloc(FD * 4);
  float* wdv = (float*)alloc(FD * 4);
  int* counts  = (int*)alloc((size_t)ND * 4);
  int* offsets = (int*)alloc((size_t)(ND + 1) * 4);
  int* cursor  = (int*)alloc((size_t)ND * 4);
  int* slots   = (int*)alloc((size_t)(E_DD + ND) * 4);
  int* mask    = (int*)alloc((size_t)ND * 4);
  int* list    = (int*)alloc((size_t)ND * 4);
  int* cnt     = (int*)alloc(256);
  (void)ws_size; (void)n_in; (void)in_sizes; (void)out_size;

  // --- weight prep: 7 transposes in one launch ---
  TPack tp;
  tp.d[0] = {W_src_dd, wsrcT_hi, 256, 768, 256, 0};
  tp.d[1] = {red1_w, r1T_hi, 890, 2048, 896, 192};
  tp.d[2] = {red2_w, r2T_hi, 2048, 512, 2048, 1984};
  tp.d[3] = {red3_w, r3T_hi, 512, 1536, 512, 3008};
  tp.d[4] = {r2a_w, raT_hi, 3072, 2048, 3072, 3776};
  tp.d[5] = {r2b_w, rbT_hi, 2048, 512, 2048, 9920};
  tp.d[6] = {r2c_w, rcT_hi, 512, 768, 512, 10944};
  multi_transpose<<<11328, dim3(32, 8), 0, stream>>>(tp);

  // --- GAT scalar prep + needed-dst compaction ---
  wvec_kernel<<<FD, 256, 0, stream>>>(W_src_dd, W_dst_dd, a_src_dd, a_dst_dd, wsv, wdv);
  esed_kernel<<<ND * FD / 1024, 256, 0, stream>>>(x_drug, wsv, wdv, es, ed);
  init_csr<<<ND / 256, 256, 0, stream>>>(counts, mask, cnt);
  mark_kernel<<<BATCH / 256, 256, 0, stream>>>(drug1_id, drug2_id, mask);
  compact_kernel<<<ND / 256, 256, 0, stream>>>(mask, cnt, list);

  // --- cell MLP (pure bf16: validated error ladder) ---
  l2norm_bf16<<<BATCH, 256, 0, stream>>>(cellf, cn_hi, 890, 896);
  mfma_gemm<1, 1, 1, 1, 0, 0, 0><<<dim3(BATCH / 128, 2048 / 128), 256, 0, stream>>>(
      nullptr, cn_hi, nullptr, r1T_hi, nullptr, red1_b, nullptr, c1_hi, BATCH, 2048, 896);
  mfma_gemm<4, 0, 0, 0, 0, 0, 0><<<dim3(BATCH / 128, 512 / 128, 4), 256, 0, stream>>>(
      nullptr, c1_hi, nullptr, r2T_hi, nullptr, nullptr, P, nullptr, BATCH, 512, 2048);
  reduce_split_ks<4><<<BATCH * 512 / 1024, 256, 0, stream>>>(P, red2_b, c2_hi, BATCH, 512);
  mfma_gemm<1, 1, 1, 1, 0, 0, 0><<<dim3(BATCH / 128, 1536 / 128), 256, 0, stream>>>(
      nullptr, c2_hi, nullptr, r3T_hi, nullptr, red3_b, nullptr, c3, BATCH, 1536, 512);

  // --- GAT (bf16x2: exact-A x rounded-B; hs stored bf16) ---
  mfma_gemm<1, 1, 0, 0, 1, 1, 0><<<dim3(ND / 128, CDIM / 128), 256, 0, stream>>>(
      x_drug, nullptr, nullptr, wsrcT_hi, nullptr, nullptr, nullptr, hs, ND, CDIM, FD);
  count_edges<<<E_DD / 256, 256, 0, stream>>>(dd_dst, counts);
  scan_kernel<<<1, 512, 0, stream>>>(counts, offsets, cursor, slots);
  scatter_edges<<<E_DD / 256, 256, 0, stream>>>(dd_src, dd_dst, cursor, slots);
  gat_aggregate<<<ND / 4, 256, 0, stream>>>(hs, es, ed, offsets, slots, b_dd, list, cnt, drug);

  // --- gather + concat + l2norm -> bf16 (hidden aliases hs; last read of drug) ---
  hidden_build_bf16<<<BATCH, 256, 0, stream>>>(drug, c3, drug1_id, drug2_id, hid_hi);

  // --- head MLP, pure bf16; r2a KS=1 + fused bf16 epilogue (R10 optimum) ---
  mfma_gemm<1, 1, 1, 1, 0, 0, 0><<<dim3(BATCH / 128, 2048 / 128), 256, 0, stream>>>(
      nullptr, hid_hi, nullptr, raT_hi, nullptr, r2a_b, nullptr, c1_hi, BATCH, 2048, 3072);
  mfma_gemm<4, 0, 0, 0, 0, 0, 0><<<dim3(BATCH / 128, 512 / 128, 4), 256, 0, stream>>>(
      nullptr, c1_hi, nullptr, rbT_hi, nullptr, nullptr, P, nullptr, BATCH, 512, 2048);
  reduce_split_ks<4><<<BATCH * 512 / 1024, 256, 0, stream>>>(P, r2b_b, c2_hi, BATCH, 512);
  mfma_gemm<2, 0, 0, 0, 0, 0, 0><<<dim3(BATCH / 128, CDIM / 128, 2), 256, 0, stream>>>(
      nullptr, c2_hi, nullptr, rcT_hi, nullptr, nullptr, P, nullptr, BATCH, CDIM, 512);
  reduce_cls<<<BATCH / 4, 256, 0, stream>>>(P, r2c_b, cls_w, cls_b, out);
}

// Round 13
// 479.585 us; speedup vs baseline: 1.0604x; 1.0256x over previous
//
#include <hip/hip_runtime.h>
#include <cstdint>

#define ND 16384
#define BATCH 4096
#define CDIM 768
#define E_DD 131072
#define FD 256

typedef unsigned short u16;
typedef u16 u16x4 __attribute__((ext_vector_type(4)));
typedef u16 u16x8 __attribute__((ext_vector_type(8)));
typedef short s16x8 __attribute__((ext_vector_type(8)));
typedef float f32x4 __attribute__((ext_vector_type(4)));

__device__ __forceinline__ u16 f2bf(float x) {
  union { float f; uint32_t u; } v; v.f = x;
  uint32_t r = v.u + 0x7fffu + ((v.u >> 16) & 1u);
  return (u16)(r >> 16);
}
__device__ __forceinline__ float bf2f(u16 h) {
  union { float f; uint32_t u; } v; v.u = ((uint32_t)h) << 16;
  return v.f;
}
// (hi << 16) | lo ; hi = bf16(x), lo = bf16(x - hi)
__device__ __forceinline__ uint32_t split2p(float x) {
  u16 h = f2bf(x);
  u16 l = f2bf(x - bf2f(h));
  return ((uint32_t)h << 16) | l;
}

// ---------------------------------------------------------------------------
// MFMA GEMM core (device fn), 128x128 tile, BK=32, 4 waves (2x2), 16x16x32.
// R5-proven staging: 4 threads/row cover 64B, KP=40 pitch.
// ALO/BLO: hi+lo error-compensation. ASPLIT: fp32 A split on load.
// Shared memory passed in flat: As (AARR*128*KP), Bs (BARR*128*KP).
// ---------------------------------------------------------------------------
#define KP 40

template <int KS, int OUT_BF16, int RELU, int BIAS, int ASPLIT, int ALO, int BLO>
__device__ __forceinline__ void gemm_core(
    int bx, int by, int bz,
    const float* __restrict__ Af,
    const u16* __restrict__ Ahi, const u16* __restrict__ Alo,
    const u16* __restrict__ Bhi, const u16* __restrict__ Blo,
    const float* __restrict__ bias,
    float* __restrict__ Cf, u16* __restrict__ Chi,
    int M, int N, int K, u16* AsB, u16* BsB) {
  constexpr int MT = 4, NT = 4;
  constexpr int BM = 128, BN = 128;
  constexpr int ASEG = BM / 64;
  constexpr int BSEG = BN / 64;

  const int t = threadIdx.x;
  const int bm0 = bx * BM, bn0 = by * BN;
  const int wid = t >> 6, lane = t & 63;
  const int quad = lane >> 4, l16 = lane & 15;
  const int wm0 = (wid >> 1) * (MT * 16);
  const int wn0 = (wid & 1) * (NT * 16);

  const int chunk = K / KS;
  const int kbeg = (KS > 1) ? bz * chunk : 0;
  const int kend = kbeg + chunk;

  auto As = [&](int a, int r, int k) -> u16& { return AsB[(a * BM + r) * KP + k]; };
  auto Bs = [&](int a, int r, int k) -> u16& { return BsB[(a * BN + r) * KP + k]; };

  f32x4 acc[MT][NT];
#pragma unroll
  for (int i = 0; i < MT; ++i)
#pragma unroll
    for (int j = 0; j < NT; ++j) acc[i][j] = (f32x4){0.f, 0.f, 0.f, 0.f};

  u16x8 pAh[ASEG], pAl[ASEG], pBh[BSEG], pBl[BSEG];

  auto loadA = [&](int c, int kk) {
    int s = t + 256 * c, row = s >> 2, kq = (s & 3) * 8;
    size_t off = (size_t)(bm0 + row) * K + kk + kq;
    if (ASPLIT) {
      f32x4 v0 = *(const f32x4*)(Af + off);
      f32x4 v1 = *(const f32x4*)(Af + off + 4);
      u16x8 h, l;
#pragma unroll
      for (int e = 0; e < 4; ++e) {
        uint32_t p = split2p(v0[e]);
        h[e] = (u16)(p >> 16); l[e] = (u16)(p & 0xffffu);
        uint32_t q = split2p(v1[e]);
        h[e + 4] = (u16)(q >> 16); l[e + 4] = (u16)(q & 0xffffu);
      }
      pAh[c] = h; pAl[c] = l;
    } else {
      pAh[c] = *(const u16x8*)(Ahi + off);
      if (ALO) pAl[c] = *(const u16x8*)(Alo + off);
    }
  };
  auto loadB = [&](int c, int kk) {
    int s = t + 256 * c, row = s >> 2, kq = (s & 3) * 8;
    size_t off = (size_t)(bn0 + row) * K + kk + kq;
    pBh[c] = *(const u16x8*)(Bhi + off);
    if (BLO) pBl[c] = *(const u16x8*)(Blo + off);
  };

#pragma unroll
  for (int c = 0; c < ASEG; ++c) loadA(c, kbeg);
#pragma unroll
  for (int c = 0; c < BSEG; ++c) loadB(c, kbeg);

  for (int k0 = kbeg;;) {
    __syncthreads();
#pragma unroll
    for (int c = 0; c < ASEG; ++c) {
      int s = t + 256 * c, row = s >> 2, kq = (s & 3) * 8;
      *(u16x8*)&As(0, row, kq) = pAh[c];
      if (ALO) *(u16x8*)&As(1, row, kq) = pAl[c];
    }
#pragma unroll
    for (int c = 0; c < BSEG; ++c) {
      int s = t + 256 * c, row = s >> 2, kq = (s & 3) * 8;
      *(u16x8*)&Bs(0, row, kq) = pBh[c];
      if (BLO) *(u16x8*)&Bs(1, row, kq) = pBl[c];
    }
    __syncthreads();

    int kn = k0 + 32;
    if (kn < kend) {
#pragma unroll
      for (int c = 0; c < ASEG; ++c) loadA(c, kn);
#pragma unroll
      for (int c = 0; c < BSEG; ++c) loadB(c, kn);
    }

    s16x8 ah[MT], al[MT], bh[NT], bl[NT];
#pragma unroll
    for (int mi = 0; mi < MT; ++mi) {
      ah[mi] = *(const s16x8*)&As(0, wm0 + mi * 16 + l16, quad * 8);
      if (ALO) al[mi] = *(const s16x8*)&As(1, wm0 + mi * 16 + l16, quad * 8);
    }
#pragma unroll
    for (int ni = 0; ni < NT; ++ni) {
      bh[ni] = *(const s16x8*)&Bs(0, wn0 + ni * 16 + l16, quad * 8);
      if (BLO) bl[ni] = *(const s16x8*)&Bs(1, wn0 + ni * 16 + l16, quad * 8);
    }
#pragma unroll
    for (int mi = 0; mi < MT; ++mi)
#pragma unroll
      for (int ni = 0; ni < NT; ++ni) {
        acc[mi][ni] = __builtin_amdgcn_mfma_f32_16x16x32_bf16(
            ah[mi], bh[ni], acc[mi][ni], 0, 0, 0);
        if (BLO)
          acc[mi][ni] = __builtin_amdgcn_mfma_f32_16x16x32_bf16(
              ah[mi], bl[ni], acc[mi][ni], 0, 0, 0);
        if (ALO)
          acc[mi][ni] = __builtin_amdgcn_mfma_f32_16x16x32_bf16(
              al[mi], bh[ni], acc[mi][ni], 0, 0, 0);
      }
    k0 = kn;
    if (k0 >= kend) break;
  }

  // D row = quad*4 + reg, col = l16 (m89/m91 layout)
  float* Cp = (KS > 1) ? Cf + (size_t)bz * M * N : Cf;
#pragma unroll
  for (int mi = 0; mi < MT; ++mi) {
#pragma unroll
    for (int ni = 0; ni < NT; ++ni) {
      int row = bm0 + wm0 + mi * 16 + quad * 4;
      int col = bn0 + wn0 + ni * 16 + l16;
      float bv = BIAS ? bias[col] : 0.f;
#pragma unroll
      for (int r = 0; r < 4; ++r) {
        float v = acc[mi][ni][r] + bv;
        if (RELU) v = fmaxf(v, 0.f);
        size_t o = (size_t)(row + r) * N + col;
        if (OUT_BF16) Chi[o] = f2bf(v);
        else Cp[o] = v;
      }
    }
  }
}

// Standalone GEMM kernel
template <int KS, int OUT_BF16, int RELU, int BIAS, int ASPLIT, int ALO, int BLO>
__global__ __launch_bounds__(256) void mfma_gemm(
    const float* __restrict__ Af,
    const u16* __restrict__ Ahi, const u16* __restrict__ Alo,
    const u16* __restrict__ Bhi, const u16* __restrict__ Blo,
    const float* __restrict__ bias,
    float* __restrict__ Cf, u16* __restrict__ Chi,
    int M, int N, int K) {
  __shared__ __align__(16) u16 AsB[(ALO ? 2 : 1) * 128 * KP];
  __shared__ __align__(16) u16 BsB[(BLO ? 2 : 1) * 128 * KP];
  gemm_core<KS, OUT_BF16, RELU, BIAS, ASPLIT, ALO, BLO>(
      blockIdx.x, blockIdx.y, (KS > 1) ? (int)blockIdx.z : 0,
      Af, Ahi, Alo, Bhi, Blo, bias, Cf, Chi, M, N, K, AsB, BsB);
}

// ---------------------------------------------------------------------------
// DUAL launch: red1 (cell MLP layer1, blocks 0..511) + hs (GAT projection,
// blocks 512..1279). Independent GEMMs co-scheduled in one grid so their
// latency stalls interleave (both are grid-limited alone at ~2 blocks/CU).
// ---------------------------------------------------------------------------
__global__ __launch_bounds__(256) void dual_gemm_red1_hs(
    const u16* __restrict__ cn, const u16* __restrict__ r1T,
    const float* __restrict__ red1_b, u16* __restrict__ c1,
    const float* __restrict__ xd, const u16* __restrict__ wsrcT,
    u16* __restrict__ hs) {
  __shared__ __align__(16) u16 AsB[2 * 128 * KP];  // max of both paths
  __shared__ __align__(16) u16 BsB[128 * KP];
  int b = blockIdx.x;
  if (b < 512) {
    // red1: M=4096, N=2048, K=896; grid 32 x 16
    gemm_core<1, 1, 1, 1, 0, 0, 0>(b & 31, b >> 5, 0, nullptr, cn, nullptr,
                                   r1T, nullptr, red1_b, nullptr, c1,
                                   BATCH, 2048, 896, AsB, BsB);
  } else {
    // hs: M=16384, N=768, K=256; grid 128 x 6 (bf16x2: fp32-A split, rounded-B)
    int b2 = b - 512;
    gemm_core<1, 1, 0, 0, 1, 1, 0>(b2 & 127, b2 >> 7, 0, xd, nullptr, nullptr,
                                   wsrcT, nullptr, nullptr, nullptr, hs,
                                   ND, CDIM, FD, AsB, BsB);
  }
}

// ---------------------------------------------------------------------------
// Split-K reduce: sum KS fp32 partials, +bias, relu, round to bf16.
// ---------------------------------------------------------------------------
template <int KS>
__global__ void reduce_split_ks(const float* __restrict__ P,
                                const float* __restrict__ bias,
                                u16* __restrict__ Chi, int M, int N) {
  int i = blockIdx.x * 256 + threadIdx.x;
  int total = (M * N) >> 2;
  if (i >= total) return;
  f32x4 s = ((const f32x4*)P)[i];
#pragma unroll
  for (int z = 1; z < KS; ++z) s += ((const f32x4*)P)[(size_t)z * total + i];
  int col = (i * 4) % N;
  f32x4 bv = *(const f32x4*)(bias + col);
  u16x4 h;
#pragma unroll
  for (int e = 0; e < 4; ++e) h[e] = f2bf(fmaxf(s[e] + bv[e], 0.f));
  *(u16x4*)&Chi[i * 4] = h;
}

// ---------------------------------------------------------------------------
// r2c reduce fused with classifier. One wave per row.
// ---------------------------------------------------------------------------
__global__ void reduce_cls(const float* __restrict__ P,
                           const float* __restrict__ bias,
                           const float* __restrict__ clsw,
                           const float* __restrict__ clsb,
                           float* __restrict__ out) {
  int row = blockIdx.x * 4 + (threadIdx.x >> 6);
  int lane = threadIdx.x & 63;
  const f32x4* p0 = (const f32x4*)(P + (size_t)row * CDIM);
  const f32x4* p1 = (const f32x4*)(P + (size_t)BATCH * CDIM + (size_t)row * CDIM);
  float s0 = 0.f, s1 = 0.f;
#pragma unroll
  for (int i = 0; i < 3; ++i) {
    int c4 = lane + 64 * i;
    f32x4 a = p0[c4] + p1[c4];
    f32x4 bv = *(const f32x4*)(bias + c4 * 4);
#pragma unroll
    for (int e = 0; e < 4; ++e) {
      float h = fmaxf(a[e] + bv[e], 0.f);
      int c = c4 * 4 + e;
      s0 = fmaf(h, clsw[c * 2 + 0], s0);
      s1 = fmaf(h, clsw[c * 2 + 1], s1);
    }
  }
#pragma unroll
  for (int m = 32; m; m >>= 1) {
    s0 += __shfl_xor(s0, m);
    s1 += __shfl_xor(s1, m);
  }
  if (lane == 0) {
    out[row * 2 + 0] = s0 + clsb[0];
    out[row * 2 + 1] = s1 + clsb[1];
  }
}

// ---------------------------------------------------------------------------
// Multi-matrix weight transpose: W fp32 [K][N] -> bf16 [N][Kpad].
// ---------------------------------------------------------------------------
struct TDesc {
  const float* W;
  u16* Th;
  int K, N, Kpad, start;
};
struct TPack { TDesc d[7]; };

__global__ void multi_transpose(TPack p) {
  __shared__ float tile[32][33];
  int b = blockIdx.x;
  int mi = 0;
#pragma unroll
  for (int i = 1; i < 7; ++i)
    if (b >= p.d[i].start) mi = i;
  TDesc dd = p.d[mi];
  int rel = b - dd.start;
  int tilesX = dd.Kpad / 32;
  int k0 = (rel % tilesX) * 32, n0 = (rel / tilesX) * 32;
  int tx = threadIdx.x, ty = threadIdx.y;
#pragma unroll
  for (int i = 0; i < 4; ++i) {
    int k = k0 + ty + 8 * i, n = n0 + tx;
    tile[ty + 8 * i][tx] = (k < dd.K && n < dd.N) ? dd.W[(size_t)k * dd.N + n] : 0.f;
  }
  __syncthreads();
#pragma unroll
  for (int i = 0; i < 4; ++i) {
    int n = n0 + ty + 8 * i, k = k0 + tx;
    if (n < dd.N) dd.Th[(size_t)n * dd.Kpad + k] = f2bf(tile[tx][ty + 8 * i]);
  }
}

// ---------------------------------------------------------------------------
// wsv[k] = sum_c W_src[k,c]*a_src[c] ; wdv[k] = sum_c W_dst[k,c]*a_dst[c]
// ---------------------------------------------------------------------------
__global__ void wvec_kernel(const float* __restrict__ Wsrc,
                            const float* __restrict__ Wdst,
                            const float* __restrict__ a_s,
                            const float* __restrict__ a_d,
                            float* __restrict__ wsv, float* __restrict__ wdv) {
  int k = blockIdx.x;
  int t = threadIdx.x;
  __shared__ float rs[256], rd[256];
  float s = 0.f, d = 0.f;
  for (int c = t; c < CDIM; c += 256) {
    s += Wsrc[(size_t)k * CDIM + c] * a_s[c];
    d += Wdst[(size_t)k * CDIM + c] * a_d[c];
  }
  rs[t] = s; rd[t] = d;
  __syncthreads();
  for (int st = 128; st; st >>= 1) {
    if (t < st) { rs[t] += rs[t + st]; rd[t] += rd[t + st]; }
    __syncthreads();
  }
  if (t == 0) { wsv[k] = rs[0]; wdv[k] = rd[0]; }
}

// es[row] = x[row].wsv ; ed[row] = x[row].wdv — one wave per row, float4.
__global__ void esed_kernel(const float* __restrict__ x,
                            const float* __restrict__ wsv,
                            const float* __restrict__ wdv,
                            float* __restrict__ es, float* __restrict__ ed) {
  int i = blockIdx.x * 256 + threadIdx.x;  // float4 index
  int lane = threadIdx.x & 63;
  int row = i >> 6;
  int c4 = lane * 4;
  f32x4 v = ((const f32x4*)x)[i];
  f32x4 ws = *(const f32x4*)(wsv + c4);
  f32x4 wd = *(const f32x4*)(wdv + c4);
  float a = v[0] * ws[0] + v[1] * ws[1] + v[2] * ws[2] + v[3] * ws[3];
  float b = v[0] * wd[0] + v[1] * wd[1] + v[2] * wd[2] + v[3] * wd[3];
#pragma unroll
  for (int m = 32; m; m >>= 1) {
    a += __shfl_xor(a, m);
    b += __shfl_xor(b, m);
  }
  if (lane == 0) { es[row] = a; ed[row] = b; }
}

// ---------------------------------------------------------------------------
// Fused init: counts=1 (self loop), mask=0, cnt=0.
// ---------------------------------------------------------------------------
__global__ void init_csr(int* counts, int* mask, int* cnt) {
  int i = blockIdx.x * 256 + threadIdx.x;
  if (i < ND) { counts[i] = 1; mask[i] = 0; }
  if (i == 0) *cnt = 0;
}
__global__ void mark_kernel(const int* __restrict__ d1, const int* __restrict__ d2,
                            int* mask) {
  int i = blockIdx.x * 256 + threadIdx.x;
  if (i < BATCH) {
    mask[d1[i]] = 1;
    mask[d2[i]] = 1;
  }
}
__global__ void compact_kernel(const int* __restrict__ mask, int* cnt, int* list) {
  int i = blockIdx.x * 256 + threadIdx.x;
  if (i < ND && mask[i]) {
    int pos = atomicAdd(cnt, 1);
    list[pos] = i;
  }
}

// ---------------------------------------------------------------------------
// CSR build (dst-sorted, self loop at segment head)
// ---------------------------------------------------------------------------
__global__ void count_edges(const int* __restrict__ dst, int* counts) {
  int e = blockIdx.x * 256 + threadIdx.x;
  if (e < E_DD) atomicAdd(&counts[dst[e]], 1);
}
// scan + self-loop head placement + cursor init, fused (single block).
__global__ void scan_kernel(const int* __restrict__ counts, int* __restrict__ offsets,
                            int* __restrict__ cursor, int* __restrict__ slots) {
  __shared__ int part[512];
  int t = threadIdx.x;
  int base = t * 32;
  int s = 0;
  for (int i = 0; i < 32; ++i) s += counts[base + i];
  part[t] = s;
  __syncthreads();
  if (t == 0) {
    int run = 0;
    for (int i = 0; i < 512; ++i) { int tmp = part[i]; part[i] = run; run += tmp; }
    offsets[ND] = run;
  }
  __syncthreads();
  int run = part[t];
  for (int i = 0; i < 32; ++i) {
    int d = base + i;
    offsets[d] = run;
    slots[run] = d;
    cursor[d] = run + 1;
    run += counts[d];
  }
}
__global__ void scatter_edges(const int* __restrict__ src, const int* __restrict__ dst,
                              int* cursor, int* slots) {
  int e = blockIdx.x * 256 + threadIdx.x;
  if (e < E_DD) {
    int pos = atomicAdd(&cursor[dst[e]], 1);
    slots[pos] = src[e];
  }
}

// ---------------------------------------------------------------------------
// GAT aggregation over COMPACTED dst list. One wave per dst; shuffle
// reductions; bf16 hs/out with wide loads (u16x8 + u16x4 = 24B/lane/row).
// ---------------------------------------------------------------------------
__global__ __launch_bounds__(256) void gat_aggregate(
    const u16* __restrict__ hs, const float* __restrict__ es,
    const float* __restrict__ ed, const int* __restrict__ offsets,
    const int* __restrict__ slots, const float* __restrict__ bias,
    const int* __restrict__ list, const int* __restrict__ cnt,
    u16* __restrict__ out) {
  int idx = blockIdx.x * 4 + (threadIdx.x >> 6);
  if (idx >= *cnt) return;
  int d = list[idx];
  int lane = threadIdx.x & 63;
  int beg = offsets[d], end = offsets[d + 1];
  float edv = ed[d];
  float mx = -1e30f;
  for (int j = beg + lane; j < end; j += 64) {
    float e = es[slots[j]] + edv;
    e = e >= 0.f ? e : 0.2f * e;
    mx = fmaxf(mx, e);
  }
#pragma unroll
  for (int m = 32; m; m >>= 1) mx = fmaxf(mx, __shfl_xor(mx, m));
  float sm = 0.f;
  for (int j = beg + lane; j < end; j += 64) {
    float e = es[slots[j]] + edv;
    e = e >= 0.f ? e : 0.2f * e;
    sm += expf(e - mx);
  }
#pragma unroll
  for (int m = 32; m; m >>= 1) sm += __shfl_xor(sm, m);
  float inv = 1.f / (sm + 1e-16f);
  int c8 = lane * 8;          // cols 0..511
  int c4 = 512 + lane * 4;    // cols 512..767
  float a8[8] = {};
  float a4[4] = {};
  for (int j = beg; j < end; ++j) {
    int srcn = slots[j];
    float e = es[srcn] + edv;
    e = e >= 0.f ? e : 0.2f * e;
    float alpha = expf(e - mx) * inv;
    const u16* hrow = hs + (size_t)srcn * CDIM;
    u16x8 r8 = *(const u16x8*)(hrow + c8);
    u16x4 r4 = *(const u16x4*)(hrow + c4);
#pragma unroll
    for (int e2 = 0; e2 < 8; ++e2) a8[e2] = fmaf(alpha, bf2f(r8[e2]), a8[e2]);
#pragma unroll
    for (int e2 = 0; e2 < 4; ++e2) a4[e2] = fmaf(alpha, bf2f(r4[e2]), a4[e2]);
  }
  u16* orow = out + (size_t)d * CDIM;
  u16x8 o8;
  u16x4 o4;
#pragma unroll
  for (int e2 = 0; e2 < 8; ++e2) o8[e2] = f2bf(fmaxf(a8[e2] + bias[c8 + e2], 0.f));
#pragma unroll
  for (int e2 = 0; e2 < 4; ++e2) o4[e2] = f2bf(fmaxf(a4[e2] + bias[c4 + e2], 0.f));
  *(u16x8*)(orow + c8) = o8;
  *(u16x4*)(orow + c4) = o4;
}

// ---------------------------------------------------------------------------
// cell l2norm -> bf16 [BATCH][Lp], zero pad L..Lp
// ---------------------------------------------------------------------------
__global__ void l2norm_bf16(const float* __restrict__ in, u16* __restrict__ hi,
                            int L, int Lp) {
  int row = blockIdx.x;
  int t = threadIdx.x;
  __shared__ float red[256];
  const float* irow = in + (size_t)row * L;
  float s = 0.f;
  for (int c = t; c < L; c += 256) { float v = irow[c]; s += v * v; }
  red[t] = s;
  __syncthreads();
  for (int st = 128; st; st >>= 1) {
    if (t < st) red[t] += red[t + st];
    __syncthreads();
  }
  float inv = 1.f / fmaxf(sqrtf(red[0]), 1e-12f);
  for (int c = t; c < Lp; c += 256) {
    float v = (c < L) ? irow[c] * inv : 0.f;
    hi[(size_t)row * Lp + c] = f2bf(v);
  }
}

// hidden = l2norm(concat(drug[d1], drug[d2], cell3)) -> bf16 [B][3072]
__global__ __launch_bounds__(256) void hidden_build_bf16(
    const u16* __restrict__ drug, const u16* __restrict__ c3,
    const int* __restrict__ d1, const int* __restrict__ d2,
    u16* __restrict__ hhi) {
  int row = blockIdx.x;
  int t = threadIdx.x;
  const u16* s1 = drug + (size_t)d1[row] * CDIM;
  const u16* s2 = drug + (size_t)d2[row] * CDIM;
  const u16* s3 = c3 + (size_t)row * (2 * CDIM);
  float vals[12];
  float ss = 0.f;
#pragma unroll
  for (int i = 0; i < 12; ++i) {
    int c = t + 256 * i;
    float v;
    if (i < 3)      v = bf2f(s1[c]);
    else if (i < 6) v = bf2f(s2[c - CDIM]);
    else            v = bf2f(s3[c - 2 * CDIM]);
    vals[i] = v;
    ss += v * v;
  }
  __shared__ float red[256];
  red[t] = ss;
  __syncthreads();
  for (int st = 128; st; st >>= 1) {
    if (t < st) red[t] += red[t + st];
    __syncthreads();
  }
  float inv = 1.f / fmaxf(sqrtf(red[0]), 1e-12f);
  u16* hrow_h = hhi + (size_t)row * (4 * CDIM);
#pragma unroll
  for (int i = 0; i < 12; ++i) hrow_h[t + 256 * i] = f2bf(vals[i] * inv);
}

// ---------------------------------------------------------------------------
extern "C" void kernel_launch(void* const* d_in, const int* in_sizes, int n_in,
                              void* d_out, int out_size, void* d_ws, size_t ws_size,
                              hipStream_t stream) {
  const float* x_drug   = (const float*)d_in[0];
  const float* cellf    = (const float*)d_in[2];
  const float* W_src_dd = (const float*)d_in[3];
  const float* W_dst_dd = (const float*)d_in[4];
  const float* a_src_dd = (const float*)d_in[5];
  const float* a_dst_dd = (const float*)d_in[6];
  const float* b_dd     = (const float*)d_in[7];
  const float* red1_w = (const float*)d_in[18];
  const float* red1_b = (const float*)d_in[19];
  const float* red2_w = (const float*)d_in[20];
  const float* red2_b = (const float*)d_in[21];
  const float* red3_w = (const float*)d_in[22];
  const float* red3_b = (const float*)d_in[23];
  const float* r2a_w  = (const float*)d_in[24];
  const float* r2a_b  = (const float*)d_in[25];
  const float* r2b_w  = (const float*)d_in[26];
  const float* r2b_b  = (const float*)d_in[27];
  const float* r2c_w  = (const float*)d_in[28];
  const float* r2c_b  = (const float*)d_in[29];
  const float* cls_w  = (const float*)d_in[30];
  const float* cls_b  = (const float*)d_in[31];
  const int* drug1_id = (const int*)d_in[32];
  const int* drug2_id = (const int*)d_in[33];
  const int* ei_dd    = (const int*)d_in[34];
  float* out = (float*)d_out;

  const int* dd_src = ei_dd;
  const int* dd_dst = ei_dd + E_DD;

  char* w = (char*)d_ws;
  size_t off = 0;
  auto alloc = [&](size_t bytes) -> char* {
    char* p = w + off;
    off = (off + bytes + 255) & ~(size_t)255;
    return p;
  };
  // bf16 intermediates (all re-rounded downstream; validated error ladder)
  u16* hs   = (u16*)alloc((size_t)ND * CDIM * 2);            // reused as hidden bf16
  u16* drug = (u16*)alloc((size_t)ND * CDIM * 2);
  u16* c3   = (u16*)alloc((size_t)BATCH * 2 * CDIM * 2);
  float* P  = (float*)alloc((size_t)4 * BATCH * 512 * 4);    // split-K partials
  u16* hid_hi = hs;  // alias: ND*CDIM == BATCH*4*CDIM
  // bf16 activations
  u16* cn_hi = (u16*)alloc((size_t)BATCH * 896 * 2);
  u16* c1_hi = (u16*)alloc((size_t)BATCH * 2048 * 2);        // shared with h1
  u16* c2_hi = (u16*)alloc((size_t)BATCH * 512 * 2);         // shared with h2
  // transposed weights [N][Kpad] — single bf16
  u16* wsrcT_hi = (u16*)alloc((size_t)CDIM * FD * 2);
  u16* r1T_hi = (u16*)alloc((size_t)2048 * 896 * 2);
  u16* r2T_hi = (u16*)alloc((size_t)512 * 2048 * 2);
  u16* r3T_hi = (u16*)alloc((size_t)1536 * 512 * 2);
  u16* raT_hi = (u16*)alloc((size_t)2048 * 3072 * 2);
  u16* rbT_hi = (u16*)alloc((size_t)512 * 2048 * 2);
  u16* rcT_hi = (u16*)alloc((size_t)768 * 512 * 2);
  // GAT scalars / CSR / dst-compaction
  float* es  = (float*)alloc((size_t)ND * 4);
  float* ed  = (float*)alloc((size_t)ND * 4);
  float* wsv = (float*)alloc(FD * 4);
  float* wdv = (float*)alloc(FD * 4);
  int* counts  = (int*)alloc((size_t)ND * 4);
  int* offsets = (int*)alloc((size_t)(ND + 1) * 4);
  int* cursor  = (int*)alloc((size_t)ND * 4);
  int* slots   = (int*)alloc((size_t)(E_DD + ND) * 4);
  int* mask    = (int*)alloc((size_t)ND * 4);
  int* list    = (int*)alloc((size_t)ND * 4);
  int* cnt     = (int*)alloc(256);
  (void)ws_size; (void)n_in; (void)in_sizes; (void)out_size;

  // --- weight prep: 7 transposes in one launch ---
  TPack tp;
  tp.d[0] = {W_src_dd, wsrcT_hi, 256, 768, 256, 0};
  tp.d[1] = {red1_w, r1T_hi, 890, 2048, 896, 192};
  tp.d[2] = {red2_w, r2T_hi, 2048, 512, 2048, 1984};
  tp.d[3] = {red3_w, r3T_hi, 512, 1536, 512, 3008};
  tp.d[4] = {r2a_w, raT_hi, 3072, 2048, 3072, 3776};
  tp.d[5] = {r2b_w, rbT_hi, 2048, 512, 2048, 9920};
  tp.d[6] = {r2c_w, rcT_hi, 512, 768, 512, 10944};
  multi_transpose<<<11328, dim3(32, 8), 0, stream>>>(tp);

  // --- GAT scalar prep + needed-dst compaction + cell l2norm ---
  wvec_kernel<<<FD, 256, 0, stream>>>(W_src_dd, W_dst_dd, a_src_dd, a_dst_dd, wsv, wdv);
  esed_kernel<<<ND * FD / 1024, 256, 0, stream>>>(x_drug, wsv, wdv, es, ed);
  init_csr<<<ND / 256, 256, 0, stream>>>(counts, mask, cnt);
  mark_kernel<<<BATCH / 256, 256, 0, stream>>>(drug1_id, drug2_id, mask);
  compact_kernel<<<ND / 256, 256, 0, stream>>>(mask, cnt, list);
  l2norm_bf16<<<BATCH, 256, 0, stream>>>(cellf, cn_hi, 890, 896);

  // --- DUAL: red1 (cell MLP) + hs (GAT projection) co-scheduled ---
  dual_gemm_red1_hs<<<1280, 256, 0, stream>>>(cn_hi, r1T_hi, red1_b, c1_hi,
                                              x_drug, wsrcT_hi, hs);

  // --- cell MLP tail ---
  mfma_gemm<4, 0, 0, 0, 0, 0, 0><<<dim3(BATCH / 128, 512 / 128, 4), 256, 0, stream>>>(
      nullptr, c1_hi, nullptr, r2T_hi, nullptr, nullptr, P, nullptr, BATCH, 512, 2048);
  reduce_split_ks<4><<<BATCH * 512 / 1024, 256, 0, stream>>>(P, red2_b, c2_hi, BATCH, 512);
  mfma_gemm<1, 1, 1, 1, 0, 0, 0><<<dim3(BATCH / 128, 1536 / 128), 256, 0, stream>>>(
      nullptr, c2_hi, nullptr, r3T_hi, nullptr, red3_b, nullptr, c3, BATCH, 1536, 512);

  // --- GAT aggregation (CSR build + softmax-weighted gather) ---
  count_edges<<<E_DD / 256, 256, 0, stream>>>(dd_dst, counts);
  scan_kernel<<<1, 512, 0, stream>>>(counts, offsets, cursor, slots);
  scatter_edges<<<E_DD / 256, 256, 0, stream>>>(dd_src, dd_dst, cursor, slots);
  gat_aggregate<<<ND / 4, 256, 0, stream>>>(hs, es, ed, offsets, slots, b_dd, list, cnt, drug);

  // --- gather + concat + l2norm -> bf16 (hidden aliases hs) ---
  hidden_build_bf16<<<BATCH, 256, 0, stream>>>(drug, c3, drug1_id, drug2_id, hid_hi);

  // --- head MLP (r2a KS=1 + fused bf16 epilogue — R10 optimum) ---
  mfma_gemm<1, 1, 1, 1, 0, 0, 0><<<dim3(BATCH / 128, 2048 / 128), 256, 0, stream>>>(
      nullptr, hid_hi, nullptr, raT_hi, nullptr, r2a_b, nullptr, c1_hi, BATCH, 2048, 3072);
  mfma_gemm<4, 0, 0, 0, 0, 0, 0><<<dim3(BATCH / 128, 512 / 128, 4), 256, 0, stream>>>(
      nullptr, c1_hi, nullptr, rbT_hi, nullptr, nullptr, P, nullptr, BATCH, 512, 2048);
  reduce_split_ks<4><<<BATCH * 512 / 1024, 256, 0, stream>>>(P, r2b_b, c2_hi, BATCH, 512);
  mfma_gemm<2, 0, 0, 0, 0, 0, 0><<<dim3(BATCH / 128, CDIM / 128, 2), 256, 0, stream>>>(
      nullptr, c2_hi, nullptr, rcT_hi, nullptr, nullptr, P, nullptr, BATCH, CDIM, 512);
  reduce_cls<<<BATCH / 4, 256, 0, stream>>>(P, r2c_b, cls_w, cls_b, out);
}